// Round 13
// baseline (12378.985 us; speedup 1.0000x reference)
//
#include <hip/hip_runtime.h>
#include <math.h>

typedef short short8 __attribute__((ext_vector_type(8)));
typedef float f32x4 __attribute__((ext_vector_type(4)));
typedef unsigned long long u64;
typedef u64 u64x2 __attribute__((ext_vector_type(2)));

#define DT 0.042f
#define LSEQ 512
#define NI 96
#define NH 1024

static __device__ __forceinline__ unsigned short f2bf(float f) {
  unsigned int u = __builtin_bit_cast(unsigned int, f);
  return (unsigned short)((u + 0x7fffu + ((u >> 16) & 1u)) >> 16);
}
static __device__ __forceinline__ float bf2f(unsigned short h) {
  unsigned int u = ((unsigned int)h) << 16;
  return __builtin_bit_cast(float, u);
}
static __device__ __forceinline__ float fast_tanhf(float a) {
  float ax = __builtin_fabsf(a);
  float e = __expf(2.0f * ax);  // overflow -> inf -> t = 1, no NaN
  float t = 1.0f - 2.0f / (e + 1.0f);
  return a < 0.0f ? -t : t;
}

// Transport scoreboard (r2..r12):
//  - hy_ex DATA: sc0 (XCD L2) on verified co-XCD groups [r8]; agent/IC otherwise [r5].
//  - FLAG posts: sc0 store after wave-local vmcnt(0) drain (fast) / agent store (slow).
//  - FLAG polls: sc0 load is L1-STICKY (r9, ~20us eviction cadence); L2 atomic RMW
//    collapses under contention (r11); agent load works but costs an IC RT (~2k cy).
//    NEW: `buffer_inv` (L1-only invalidate, CU-local) before each sc0 poll load ->
//    poll served by XCD L2 (~350cy), fresh by construction.
template <bool F>
static __device__ __forceinline__ void ld16_issue(u64x2* dst, const u64* p) {
  if constexpr (F) {
    asm volatile("global_load_dwordx4 %0, %1, off sc0" : "=v"(*dst) : "v"(p) : "memory");
  } else {
    u64 a = __hip_atomic_load(p, __ATOMIC_RELAXED, __HIP_MEMORY_SCOPE_AGENT);
    u64 b = __hip_atomic_load(p + 1, __ATOMIC_RELAXED, __HIP_MEMORY_SCOPE_AGENT);
    *dst = (u64x2){a, b};
  }
}
template <bool F>
static __device__ __forceinline__ void stpub(unsigned int* p, unsigned int v) {
  if constexpr (F)
    asm volatile("global_store_dword %0, %1, off sc0" ::"v"(p), "v"(v) : "memory");
  else
    __hip_atomic_store(p, v, __ATOMIC_RELAXED, __HIP_MEMORY_SCOPE_AGENT);
}
template <bool F>
static __device__ __forceinline__ void stflag(unsigned int* p, unsigned int v) {
  if constexpr (F)
    asm volatile("global_store_dword %0, %1, off sc0" ::"v"(p), "v"(v) : "memory");
  else
    __hip_atomic_store(p, v, __ATOMIC_RELAXED, __HIP_MEMORY_SCOPE_AGENT);
}
// poll: invalidate own L1 (cheap, CU-local), then read the flag from the XCD L2
static __device__ __forceinline__ unsigned int pollflag_l2(const unsigned int* p) {
  unsigned int r;
  asm volatile("buffer_inv\n\tglobal_load_dword %0, %1, off sc0\n\ts_waitcnt vmcnt(0)"
               : "=v"(r) : "v"(p) : "memory");
  __builtin_amdgcn_sched_barrier(0);
  return r;
}
static __device__ __forceinline__ void inv_l1() {  // A-lines fresh-from-L2 guarantee
  asm volatile("buffer_inv" ::: "memory");
  __builtin_amdgcn_sched_barrier(0);
}
static __device__ __forceinline__ void st_out(float* p, float v) {
  asm volatile("global_store_dword %0, %1, off" ::"v"(p), "v"(v) : "memory");
}
static __device__ __forceinline__ void drain_vm() {  // wave-local full drain
  asm volatile("s_waitcnt vmcnt(0)" ::: "memory");
  __builtin_amdgcn_sched_barrier(0);
}
template <bool F>
static __device__ __forceinline__ void wait_A(bool pubwave) {
  if constexpr (F) {
    // pub-wave queue after spin: A(8) oldest + out(4) newest -> vmcnt(4) retires A.
    if (pubwave)
      asm volatile("s_waitcnt vmcnt(4)" ::: "memory");
    else
      asm volatile("s_waitcnt vmcnt(0)" ::: "memory");
    __builtin_amdgcn_sched_barrier(0);
  }
}
template <bool B> struct BoolC { static constexpr bool value = B; };

// 256 blocks x 512 threads. Group g (16 batch rows) x col-block jb (32 cols); 8 waves
// k-split 1024. Single-poller sync (r12): wave 0 polls the group's 64 per-wave flags
// via buffer_inv+sc0 (L2-local); a top-of-step s_barrier releases waves 1-7, which
// then buffer_inv once so their sc0 A-loads are L1-fresh. Waves 0,1 drain their own
// sc0 publishes (vmcnt(0)) then post their own sc0 flag. Triple-buffered hy_ex (r5
// invariant). out[] stores deferred one step; only L2 acks ever sit on the path.
__global__ __launch_bounds__(512, 2) void ron_kernel(
    const float* __restrict__ x, const float* __restrict__ x2h,
    const float* __restrict__ h2h, const float* __restrict__ bias,
    const float* __restrict__ gam_, const float* __restrict__ eps_,
    float* __restrict__ out, unsigned int* __restrict__ flags,
    unsigned int* __restrict__ hy_ex) {
  const int tid = threadIdx.x;
  const int w = tid >> 6;  // 0..7
  const int l = tid & 63;
  const int lc = l & 15;
  const int kg = l >> 4;

  __shared__ f32x4 part[2][8][2][64];  // 32KB, double-buffered by s&1
  __shared__ int info_sh;

  unsigned int* base = flags + 8192;  // byte 32768
  unsigned int* xcdtab = base;        // [0..255]
  unsigned int* ctr = base + 256;
  unsigned int* abortw = base + 257;
  unsigned int* enttab = base + 272;  // [0..255]

  // ---- publish my XCD (every block) ----
  if (tid == 0) {
    unsigned int myxcd = __builtin_amdgcn_s_getreg(63508) & 15u;  // hwreg(XCC_ID=20,0,32)
    __hip_atomic_store(xcdtab + blockIdx.x, 0x100u | myxcd, __ATOMIC_RELAXED,
                       __HIP_MEMORY_SCOPE_AGENT);
    __hip_atomic_fetch_add(ctr, 1u, __ATOMIC_RELAXED, __HIP_MEMORY_SCOPE_AGENT);
  }

  // ---- block 0: build the (g, jb, mode) table — single source of truth (r8-proven) ----
  if (blockIdx.x == 0 && tid == 0) {
    int gu = 0;
    while (__hip_atomic_load(ctr, __ATOMIC_RELAXED, __HIP_MEMORY_SCOPE_AGENT) < 256u) {
      if (++gu > (1 << 17)) break;
      __builtin_amdgcn_s_sleep(8);
    }
    bool ok = (gu <= (1 << 17));
    unsigned char xs[256];
    if (ok) {
      for (int i = 0; i < 256; ++i) {
        unsigned int v = __hip_atomic_load(xcdtab + i, __ATOMIC_RELAXED, __HIP_MEMORY_SCOPE_AGENT);
        int g2 = 0;
        while (v == 0 && ++g2 <= 8192) {
          __builtin_amdgcn_s_sleep(2);
          v = __hip_atomic_load(xcdtab + i, __ATOMIC_RELAXED, __HIP_MEMORY_SCOPE_AGENT);
        }
        if (v == 0) { ok = false; break; }
        xs[i] = (unsigned char)(v & 15u);
      }
    }
    unsigned int ent[256];
    if (ok) {
      int gidx = 0, nl = 0;
      unsigned char left[256], tmp[256];
      for (unsigned int xc = 0; xc < 16u && gidx < 8; ++xc) {
        int cnt = 0;
        for (int i = 0; i < 256; ++i)
          if (xs[i] == (unsigned char)xc) tmp[cnt++] = (unsigned char)i;
        int p = 0;
        while (cnt - p >= 32 && gidx < 8) {  // exact-32 co-XCD set -> fast
          for (int k2 = 0; k2 < 32; ++k2)
            ent[tmp[p + k2]] = 1u | ((unsigned)gidx << 1) | ((unsigned)k2 << 4) | (1u << 9);
          ++gidx; p += 32;
        }
        for (; p < cnt; ++p) left[nl++] = tmp[p];
      }
      int li = 0;
      while (gidx < 8) {  // mixed leftovers -> slow (agent/IC, proven)
        for (int k2 = 0; k2 < 32 && li < nl; ++k2, ++li)
          ent[left[li]] = 1u | ((unsigned)gidx << 1) | ((unsigned)k2 << 4);
        ++gidx;
      }
    } else {
      for (int i = 0; i < 256; ++i)
        ent[i] = 1u | ((unsigned)(i & 7) << 1) | ((unsigned)(i >> 3) << 4);
    }
    for (int i = 0; i < 256; ++i)
      __hip_atomic_store(enttab + i, ent[i], __ATOMIC_RELAXED, __HIP_MEMORY_SCOPE_AGENT);
  }

  // ---- every block: fetch my entry ----
  if (tid == 0) {
    unsigned int e = 0;
    int gu = 0;
    for (;;) {
      e = __hip_atomic_load(enttab + blockIdx.x, __ATOMIC_RELAXED, __HIP_MEMORY_SCOPE_AGENT);
      if (e || ++gu > (1 << 17)) break;
      __builtin_amdgcn_s_sleep(16);
    }
    if (!e) e = 1u | ((unsigned)(blockIdx.x & 7) << 1) | ((unsigned)(blockIdx.x >> 3) << 4);
    info_sh = (int)e;
  }
  __syncthreads();
  const unsigned int ent = (unsigned int)info_sh;
  const int g = (ent >> 1) & 7;
  const int jb = (ent >> 4) & 31;
  const bool fastm = ((ent >> 9) & 1) != 0;

  // ---- one-time: h2h k-slice (wave's 4 k-tiles) x 2 col-tiles, hi/lo bf16 ----
  short8 wfh[4][2], wfl[4][2];
#pragma unroll
  for (int j = 0; j < 4; ++j) {
    const int krow = (w * 4 + j) * 32 + kg * 8;
#pragma unroll
    for (int t = 0; t < 2; ++t) {
      const int c = jb * 32 + t * 16 + lc;
#pragma unroll
      for (int jj = 0; jj < 8; ++jj) {
        float v = h2h[(size_t)(krow + jj) * NH + c];
        unsigned short hb = f2bf(v);
        wfh[j][t][jj] = (short)hb;
        wfl[j][t][jj] = (short)f2bf(v - bf2f(hb));
      }
    }
  }
  const int myc = jb * 32 + w * 16 + lc;  // owned col (waves 0,1 only)
  short8 xwh[3], xwl[3];
  float bias_c = 0.f, gam = 0.f, ep = 0.f;
  if (w < 2) {
#pragma unroll
    for (int kt = 0; kt < 3; ++kt)
#pragma unroll
      for (int jj = 0; jj < 8; ++jj) {
        float v = x2h[(size_t)(kt * 32 + kg * 8 + jj) * NH + myc];
        unsigned short hb = f2bf(v);
        xwh[kt][jj] = (short)hb;
        xwl[kt][jj] = (short)f2bf(v - bf2f(hb));
      }
    bias_c = bias[myc];
    gam = gam_[myc];
    ep = eps_[myc];
  }

  float hy[4] = {0.f, 0.f, 0.f, 0.f};
  float hz[4] = {0.f, 0.f, 0.f, 0.f};
  const float* xlane = x + (size_t)(g * 16 + lc) * LSEQ * NI + kg * 8;
  const int aoff = lc * 8 + kg * 2;  // u64 units within a 128-u64 chunk
  // per-wave flags: 64 per group, 64B-spaced. Posted by waves 0,1; polled by wave 0.
  unsigned int* myflag = flags + (size_t)(g * 64 + jb * 2 + w) * 16;
  unsigned int* watch = flags + (size_t)(g * 64 + l) * 16;  // wave 0: lane l -> flag l
  const int ktc = myc >> 5, kgc = (myc >> 3) & 3, sh = myc & 7;

  // out pointers, one per accumulator row; advanced by NH each stored step
  float* op[4];
  if (w < 2) {
#pragma unroll
    for (int i = 0; i < 4; ++i)
      op[i] = out + (size_t)(g * 16 + kg * 4 + i) * LSEQ * NH + myc;
  }

  // ---- prefetch x for s=0 ----
  f32x4 xr[6];
  if (w < 2) {
#pragma unroll
    for (int kt = 0; kt < 3; ++kt) {
      xr[2 * kt] = *(const f32x4*)(xlane + kt * 32);
      xr[2 * kt + 1] = *(const f32x4*)(xlane + kt * 32 + 4);
    }
  }

  auto run = [&](auto fc) {
    constexpr bool F = decltype(fc)::value;
    bool noSync = false;  // wave 0 only; trip -> never wait again (visible failure)
    for (int s = 0; s < LSEQ; ++s) {
      const int wb = s % 3;            // write buffer
      const int rb = wb ? wb - 1 : 2;  // read buffer = (s-1)%3

      if (s) {
        // ---- single-poller spin: wave 0. Fast: buffer_inv + sc0 load (XCD L2) ----
        if (w == 0 && !noSync) {
          int guard = 0;
          for (;;) {
            unsigned int v;
            if constexpr (F)
              v = pollflag_l2(watch);
            else
              v = __hip_atomic_load(watch, __ATOMIC_RELAXED, __HIP_MEMORY_SCOPE_AGENT);
            if (!__any((int)v < s)) break;
            if ((++guard & 1023) == 0) {
              bool ab = false;
              if (l == 0)
                ab = (__hip_atomic_load(abortw, __ATOMIC_RELAXED,
                                        __HIP_MEMORY_SCOPE_AGENT) != 0u);
              if (__any(ab) || guard > (1 << 16)) {
                if (l == 0)
                  __hip_atomic_store(abortw, 1u, __ATOMIC_RELAXED, __HIP_MEMORY_SCOPE_AGENT);
                noSync = true;
                break;
              }
            }
            __builtin_amdgcn_s_sleep(1);
          }
        }
        __syncthreads();  // releases waves 1-7 (local s_barrier, zero fabric traffic)
        if constexpr (F) inv_l1();  // every wave: A-lines will be L1-fresh from L2
      }

      // ---- pack x(s) from regs loaded last iter ----
      short8 axh[3], axl[3];
      if (w < 2) {
#pragma unroll
        for (int kt = 0; kt < 3; ++kt) {
#pragma unroll
          for (int jj = 0; jj < 4; ++jj) {
            unsigned short hb = f2bf(xr[2 * kt][jj]);
            axh[kt][jj] = (short)hb;
            axl[kt][jj] = (short)f2bf(xr[2 * kt][jj] - bf2f(hb));
            unsigned short hb2 = f2bf(xr[2 * kt + 1][jj]);
            axh[kt][jj + 4] = (short)hb2;
            axl[kt][jj + 4] = (short)f2bf(xr[2 * kt + 1][jj] - bf2f(hb2));
          }
        }
      }

      f32x4 a0a = {0.f, 0.f, 0.f, 0.f}, a0b = {0.f, 0.f, 0.f, 0.f};
      f32x4 a1a = {0.f, 0.f, 0.f, 0.f}, a1b = {0.f, 0.f, 0.f, 0.f};
      f32x4 accx = {0.f, 0.f, 0.f, 0.f};
      u64x2 hq[4], lq[4];

      if (s) {
        // ---- issue A-loads FIRST (oldest in queue) ----
        const u64* srcg = (const u64*)hy_ex + (size_t)(rb * 8 + g) * 8192;
#pragma unroll
        for (int j = 0; j < 4; ++j) {
          const int idx = (w * 4 + j) * 128 + aoff;
          ld16_issue<F>(&hq[j], srcg + idx);
          ld16_issue<F>(&lq[j], srcg + 4096 + idx);
        }
        // ---- then out[s-1] stores (hy holds step s-1; acks ride under MFMAs) ----
        if (w < 2) {
#pragma unroll
          for (int i = 0; i < 4; ++i) {
            st_out(op[i], hy[i]);
            op[i] += NH;
          }
        }
      }

      // ---- x-projection MFMAs (waves 0,1): overlap the A-load round trip ----
      if (w < 2) {
#pragma unroll
        for (int kt = 0; kt < 3; ++kt) {
          accx = __builtin_amdgcn_mfma_f32_16x16x32_bf16(axh[kt], xwh[kt], accx, 0, 0, 0);
          accx = __builtin_amdgcn_mfma_f32_16x16x32_bf16(axl[kt], xwh[kt], accx, 0, 0, 0);
          accx = __builtin_amdgcn_mfma_f32_16x16x32_bf16(axh[kt], xwl[kt], accx, 0, 0, 0);
        }
      }

      if (s) {
        wait_A<F>(w < 2);  // fast: vmcnt(4) pub-waves (outs fly) / vmcnt(0) others
#pragma unroll
        for (int j = 0; j < 4; ++j) {
          short8 fh = __builtin_bit_cast(short8, hq[j]);
          short8 fl = __builtin_bit_cast(short8, lq[j]);
          if (j & 1) {
            a0b = __builtin_amdgcn_mfma_f32_16x16x32_bf16(fh, wfh[j][0], a0b, 0, 0, 0);
            a1b = __builtin_amdgcn_mfma_f32_16x16x32_bf16(fh, wfh[j][1], a1b, 0, 0, 0);
            a0b = __builtin_amdgcn_mfma_f32_16x16x32_bf16(fl, wfh[j][0], a0b, 0, 0, 0);
            a1b = __builtin_amdgcn_mfma_f32_16x16x32_bf16(fl, wfh[j][1], a1b, 0, 0, 0);
            a0b = __builtin_amdgcn_mfma_f32_16x16x32_bf16(fh, wfl[j][0], a0b, 0, 0, 0);
            a1b = __builtin_amdgcn_mfma_f32_16x16x32_bf16(fh, wfl[j][1], a1b, 0, 0, 0);
          } else {
            a0a = __builtin_amdgcn_mfma_f32_16x16x32_bf16(fh, wfh[j][0], a0a, 0, 0, 0);
            a1a = __builtin_amdgcn_mfma_f32_16x16x32_bf16(fh, wfh[j][1], a1a, 0, 0, 0);
            a0a = __builtin_amdgcn_mfma_f32_16x16x32_bf16(fl, wfh[j][0], a0a, 0, 0, 0);
            a1a = __builtin_amdgcn_mfma_f32_16x16x32_bf16(fl, wfh[j][1], a1a, 0, 0, 0);
            a0a = __builtin_amdgcn_mfma_f32_16x16x32_bf16(fh, wfl[j][0], a0a, 0, 0, 0);
            a1a = __builtin_amdgcn_mfma_f32_16x16x32_bf16(fh, wfl[j][1], a1a, 0, 0, 0);
          }
        }
      }

      // ---- cross-wave k-reduction via LDS ----
      part[s & 1][w][0][l] = a0a + a0b;
      part[s & 1][w][1][l] = a1a + a1b;
      __syncthreads();

      if (w < 2) {
        f32x4 r = accx;
#pragma unroll
        for (int ww = 0; ww < 8; ++ww) r += part[s & 1][ww][w][l];

        unsigned int* dstg = hy_ex + (size_t)(wb * 8 + g) * 16384;
#pragma unroll
        for (int i = 0; i < 4; ++i) {
          float a = r[i] + bias_c;
          float th = fast_tanhf(a);
          hz[i] += DT * (th - gam * hy[i] - ep * hz[i]);
          hy[i] += DT * hz[i];
          const int rr = kg * 4 + i;
          unsigned short hb = f2bf(hy[i]);
          unsigned short lb = f2bf(hy[i] - bf2f(hb));
          unsigned int oh = (unsigned int)__shfl_xor((int)hb, 1, 64);
          unsigned int ol = (unsigned int)__shfl_xor((int)lb, 1, 64);
          if (!(lc & 1)) {  // even col stores the (c, c+1) pair
            const int u32idx = (ktc * 512 + rr * 32 + kgc * 8 + sh) >> 1;
            stpub<F>(dstg + u32idx, (unsigned int)hb | (oh << 16));
            stpub<F>(dstg + 8192 + u32idx, (unsigned int)lb | (ol << 16));
          }
        }
        drain_vm();  // wave-local: publishes in L2 (outs retired under MFMAs)
        if (l == 0) stflag<F>(myflag, (unsigned int)(s + 1));

        // ---- x(s+1) prefetch: behind the flag post, off the critical path ----
        const float* xs2 = xlane + (size_t)(s + 1 < LSEQ ? s + 1 : s) * NI;
#pragma unroll
        for (int kt = 0; kt < 3; ++kt) {
          xr[2 * kt] = *(const f32x4*)(xs2 + kt * 32);
          xr[2 * kt + 1] = *(const f32x4*)(xs2 + kt * 32 + 4);
        }
      }
    }
    // ---- epilogue: flush the deferred final-step outputs ----
    if (w < 2) {
#pragma unroll
      for (int i = 0; i < 4; ++i) *op[i] = hy[i];
    }
  };

  if (fastm)
    run(BoolC<true>{});
  else
    run(BoolC<false>{});
}

extern "C" void kernel_launch(void* const* d_in, const int* in_sizes, int n_in,
                              void* d_out, int out_size, void* d_ws, size_t ws_size,
                              hipStream_t stream) {
  const float* x = (const float*)d_in[0];
  const float* x2h = (const float*)d_in[1];
  const float* h2h = (const float*)d_in[2];
  const float* bias = (const float*)d_in[3];
  const float* gam = (const float*)d_in[4];
  const float* eps = (const float*)d_in[5];
  float* out = (float*)d_out;

  unsigned int* flags = (unsigned int*)d_ws;                   // 32KB per-wave flags + tables
  unsigned int* hy_ex = (unsigned int*)((char*)d_ws + 65536);  // 3 bufs x 8 groups x 64KB

  // zero flags + discovery + mapping table every call (step 0 never reads hy_ex)
  hipMemsetAsync(d_ws, 0, 65536, stream);

  ron_kernel<<<dim3(256), dim3(512), 0, stream>>>(x, x2h, h2h, bias, gam, eps, out, flags, hy_ex);
}

// Round 14
// 3342.028 us; speedup vs baseline: 3.7040x; 3.7040x over previous
//
#include <hip/hip_runtime.h>
#include <math.h>

typedef short short8 __attribute__((ext_vector_type(8)));
typedef float f32x4 __attribute__((ext_vector_type(4)));
typedef unsigned long long u64;
typedef u64 u64x2 __attribute__((ext_vector_type(2)));

#define DT 0.042f
#define LSEQ 512
#define NI 96
#define NH 1024

static __device__ __forceinline__ unsigned short f2bf(float f) {
  unsigned int u = __builtin_bit_cast(unsigned int, f);
  return (unsigned short)((u + 0x7fffu + ((u >> 16) & 1u)) >> 16);
}
static __device__ __forceinline__ float bf2f(unsigned short h) {
  unsigned int u = ((unsigned int)h) << 16;
  return __builtin_bit_cast(float, u);
}
static __device__ __forceinline__ float fast_tanhf(float a) {
  float ax = __builtin_fabsf(a);
  float e = __expf(2.0f * ax);
  float t = 1.0f - 2.0f / (e + 1.0f);
  return a < 0.0f ? -t : t;
}

// DATA transport: sc0 (XCD L2) on verified co-XCD groups, sc1 (IC) otherwise.
// FLAGS: always relaxed agent atomics (r9/r11/r13 alternatives all failed).
template <bool F>
static __device__ __forceinline__ void ld16(u64x2* d, const void* p) {
  if constexpr (F)
    asm volatile("global_load_dwordx4 %0, %1, off sc0" : "=v"(*d) : "v"(p) : "memory");
  else
    asm volatile("global_load_dwordx4 %0, %1, off sc1" : "=v"(*d) : "v"(p) : "memory");
}
template <bool F>
static __device__ __forceinline__ void st4(unsigned int* p, unsigned int v) {
  if constexpr (F)
    asm volatile("global_store_dword %0, %1, off sc0" ::"v"(p), "v"(v) : "memory");
  else
    asm volatile("global_store_dword %0, %1, off sc1" ::"v"(p), "v"(v) : "memory");
}
static __device__ __forceinline__ void vmw16() {
  asm volatile("s_waitcnt vmcnt(16)" ::: "memory");
  __builtin_amdgcn_sched_barrier(0);
}
static __device__ __forceinline__ void vmw0() {
  asm volatile("s_waitcnt vmcnt(0)" ::: "memory");
  __builtin_amdgcn_sched_barrier(0);
}
static __device__ __forceinline__ void lgkm0() {
  asm volatile("s_waitcnt lgkmcnt(0)" ::: "memory");
  __builtin_amdgcn_sched_barrier(0);
}
template <bool B> struct BoolC { static constexpr bool value = B; };

// 256 blocks x 256 threads (4 waves). Group g (16 rows) x col-block jb (32 cols).
// Waves 0,1: full-K compute+publish for 16 cols each — VMEM queue holds ONLY
// poll loads / A-loads / publish+flag stores (all L2/IC, fast acks). No barriers.
// Wave 2: x HBM->LDS service. Wave 3: hy LDS->out HBM service. LDS seq-words
// (lgkmcnt domain) decouple them from the compute waves' vmcnt queues — the r8
// hidden stall (polls waiting on out-store DRAM acks / x HBM loads) is gone.
// Triple-buffered hy_ex: spin requires all 64 flags >= s (peers done s-1 =>
// done reading buf[s%3] at s-2) before writing buf[s%3] (r5 invariant).
__global__ __launch_bounds__(256, 1) void ron_kernel(
    const float* __restrict__ x, const float* __restrict__ x2h,
    const float* __restrict__ h2h, const float* __restrict__ bias,
    const float* __restrict__ gam_, const float* __restrict__ eps_,
    float* __restrict__ out, unsigned int* __restrict__ flags,
    unsigned int* __restrict__ hy_ex) {
  const int tid = threadIdx.x;
  const int w = tid >> 6;
  const int l = tid & 63;
  const int lc = l & 15;
  const int kg = l >> 4;

  __shared__ int info_sh;
  __shared__ volatile int xseq, hyseq0, hyseq1, xcons0, xcons1, outsq;
  __shared__ float xbuf[2][16][NI];      // 12KB
  __shared__ float hybuf[2][2][16][16];  // 4KB

  unsigned int* base = flags + 8192;  // byte 32768
  unsigned int* xcdtab = base;
  unsigned int* ctr = base + 256;
  unsigned int* abortw = base + 257;
  unsigned int* enttab = base + 272;

  if (tid == 0) {
    xseq = 0; hyseq0 = 0; hyseq1 = 0; xcons0 = 0; xcons1 = 0; outsq = 0;
    unsigned int myxcd = __builtin_amdgcn_s_getreg(63508) & 15u;  // XCC_ID
    __hip_atomic_store(xcdtab + blockIdx.x, 0x100u | myxcd, __ATOMIC_RELAXED,
                       __HIP_MEMORY_SCOPE_AGENT);
    __hip_atomic_fetch_add(ctr, 1u, __ATOMIC_RELAXED, __HIP_MEMORY_SCOPE_AGENT);
  }

  // ---- block 0: build (g, jb, mode) table — single source of truth (r8-proven) ----
  if (blockIdx.x == 0 && tid == 0) {
    int gu = 0;
    while (__hip_atomic_load(ctr, __ATOMIC_RELAXED, __HIP_MEMORY_SCOPE_AGENT) < 256u) {
      if (++gu > (1 << 17)) break;
      __builtin_amdgcn_s_sleep(8);
    }
    bool ok = (gu <= (1 << 17));
    unsigned char xs[256];
    if (ok) {
      for (int i = 0; i < 256; ++i) {
        unsigned int v = __hip_atomic_load(xcdtab + i, __ATOMIC_RELAXED, __HIP_MEMORY_SCOPE_AGENT);
        int g2 = 0;
        while (v == 0 && ++g2 <= 8192) {
          __builtin_amdgcn_s_sleep(2);
          v = __hip_atomic_load(xcdtab + i, __ATOMIC_RELAXED, __HIP_MEMORY_SCOPE_AGENT);
        }
        if (v == 0) { ok = false; break; }
        xs[i] = (unsigned char)(v & 15u);
      }
    }
    unsigned int ent[256];
    if (ok) {
      int gidx = 0, nl = 0;
      unsigned char left[256], tmp[256];
      for (unsigned int xc = 0; xc < 16u && gidx < 8; ++xc) {
        int cnt = 0;
        for (int i = 0; i < 256; ++i)
          if (xs[i] == (unsigned char)xc) tmp[cnt++] = (unsigned char)i;
        int p = 0;
        while (cnt - p >= 32 && gidx < 8) {
          for (int k2 = 0; k2 < 32; ++k2)
            ent[tmp[p + k2]] = 1u | ((unsigned)gidx << 1) | ((unsigned)k2 << 4) | (1u << 9);
          ++gidx; p += 32;
        }
        for (; p < cnt; ++p) left[nl++] = tmp[p];
      }
      int li = 0;
      while (gidx < 8) {
        for (int k2 = 0; k2 < 32 && li < nl; ++k2, ++li)
          ent[left[li]] = 1u | ((unsigned)gidx << 1) | ((unsigned)k2 << 4);
        ++gidx;
      }
    } else {
      for (int i = 0; i < 256; ++i)
        ent[i] = 1u | ((unsigned)(i & 7) << 1) | ((unsigned)(i >> 3) << 4);
    }
    for (int i = 0; i < 256; ++i)
      __hip_atomic_store(enttab + i, ent[i], __ATOMIC_RELAXED, __HIP_MEMORY_SCOPE_AGENT);
  }

  if (tid == 0) {
    unsigned int e = 0;
    int gu = 0;
    for (;;) {
      e = __hip_atomic_load(enttab + blockIdx.x, __ATOMIC_RELAXED, __HIP_MEMORY_SCOPE_AGENT);
      if (e || ++gu > (1 << 17)) break;
      __builtin_amdgcn_s_sleep(16);
    }
    if (!e) e = 1u | ((unsigned)(blockIdx.x & 7) << 1) | ((unsigned)(blockIdx.x >> 3) << 4);
    info_sh = (int)e;
  }
  __syncthreads();  // the ONLY block barrier
  const unsigned int ent = (unsigned int)info_sh;
  const int g = (ent >> 1) & 7;
  const int jb = (ent >> 4) & 31;
  const bool fastm = ((ent >> 9) & 1) != 0;

  // ================= SERVICE WAVES =================
  if (w == 2) {  // x: HBM -> LDS, one step ahead of consumers
    for (int s = 0; s < LSEQ; ++s) {
      if (s >= 2) {
        int gu = 0;
        while (xcons0 < s - 1 || xcons1 < s - 1) {
          if (++gu > (1 << 22)) break;
          __builtin_amdgcn_s_sleep(1);
        }
      }
      f32x4 v[6];
#pragma unroll
      for (int k = 0; k < 6; ++k) {
        const int u = l + 64 * k;  // dwordx4 unit: row u/24, f32 offset (u%24)*4
        const float* p = x + ((size_t)(g * 16 + u / 24) * LSEQ + s) * NI + (u % 24) * 4;
        v[k] = *(const f32x4*)p;
      }
#pragma unroll
      for (int k = 0; k < 6; ++k) {
        const int u = l + 64 * k;
        *(f32x4*)&xbuf[s & 1][u / 24][(u % 24) * 4] = v[k];
      }
      lgkm0();
      if (l == 0) xseq = s + 1;
    }
    return;
  }
  if (w == 3) {  // out: LDS -> HBM (all DRAM store acks live on THIS wave's queue)
    for (int s = 0; s < LSEQ; ++s) {
      int gu = 0;
      while (hyseq0 < s + 1 || hyseq1 < s + 1) {
        if (++gu > (1 << 22)) break;
        __builtin_amdgcn_s_sleep(1);
      }
      const int row = l >> 2, q = l & 3, wv = q >> 1, c0 = (q & 1) * 8;
      f32x4 a = *(const f32x4*)&hybuf[s & 1][wv][row][c0];
      f32x4 b = *(const f32x4*)&hybuf[s & 1][wv][row][c0 + 4];
      lgkm0();
      if (l == 0) outsq = s + 1;
      float* po = out + ((size_t)(g * 16 + row) * LSEQ + s) * NH + jb * 32 + q * 8;
      *(f32x4*)po = a;
      *(f32x4*)(po + 4) = b;
    }
    return;
  }

  // ================= COMPUTE WAVES (w = 0,1) =================
  short8 wfh[32], wfl[32];  // full-K weights for my 16 cols (256 VGPR)
  const int myc = jb * 32 + w * 16 + lc;
#pragma unroll
  for (int j = 0; j < 32; ++j) {
    const int krow = j * 32 + kg * 8;
#pragma unroll
    for (int jj = 0; jj < 8; ++jj) {
      float v = h2h[(size_t)(krow + jj) * NH + myc];
      unsigned short hb = f2bf(v);
      wfh[j][jj] = (short)hb;
      wfl[j][jj] = (short)f2bf(v - bf2f(hb));
    }
  }
  short8 xwh[3], xwl[3];
#pragma unroll
  for (int kt = 0; kt < 3; ++kt)
#pragma unroll
    for (int jj = 0; jj < 8; ++jj) {
      float v = x2h[(size_t)(kt * 32 + kg * 8 + jj) * NH + myc];
      unsigned short hb = f2bf(v);
      xwh[kt][jj] = (short)hb;
      xwl[kt][jj] = (short)f2bf(v - bf2f(hb));
    }
  const float bias_c = bias[myc];
  const float gam = gam_[myc];
  const float ep = eps_[myc];

  float hy[4] = {0.f, 0.f, 0.f, 0.f};
  float hz[4] = {0.f, 0.f, 0.f, 0.f};
  unsigned int* myflag = flags + (size_t)(g * 64 + jb * 2 + w) * 16;  // 64B-spaced
  unsigned int* watch = flags + (size_t)(g * 64 + l) * 16;            // lane l -> flag l

#define ISSUE(CC, BH, BL)                                                   \
  {                                                                         \
    _Pragma("unroll") for (int jj = 0; jj < 8; ++jj) {                      \
      const int off = lc * 2048 + ((CC)*8 + jj) * 64 + kg * 16;             \
      ld16<F>(&BH[jj], srcg + off);                                         \
      ld16<F>(&BL[jj], srcg + 32768 + off);                                 \
    }                                                                       \
  }
#define CRUNCH(CC, BH, BL)                                                  \
  {                                                                         \
    _Pragma("unroll") for (int jj = 0; jj < 8; ++jj) {                      \
      const int kt = (CC)*8 + jj;                                           \
      short8 fh = __builtin_bit_cast(short8, BH[jj]);                       \
      short8 fl = __builtin_bit_cast(short8, BL[jj]);                       \
      acc[(3 * kt) & 3] =                                                   \
          __builtin_amdgcn_mfma_f32_16x16x32_bf16(fh, wfh[kt], acc[(3 * kt) & 3], 0, 0, 0);      \
      acc[(3 * kt + 1) & 3] =                                               \
          __builtin_amdgcn_mfma_f32_16x16x32_bf16(fl, wfh[kt], acc[(3 * kt + 1) & 3], 0, 0, 0);  \
      acc[(3 * kt + 2) & 3] =                                               \
          __builtin_amdgcn_mfma_f32_16x16x32_bf16(fh, wfl[kt], acc[(3 * kt + 2) & 3], 0, 0, 0);  \
    }                                                                       \
  }

  auto run = [&](auto fc) {
    constexpr bool F = decltype(fc)::value;
    bool noSync = false;
    for (int s = 0; s < LSEQ; ++s) {
      const int wb = s % 3, rb = wb ? wb - 1 : 2;

      // ---- x from LDS (lgkm domain only — no vmcnt pollution) ----
      {
        int gu = 0;
        while (xseq < s + 1) {
          if (++gu > (1 << 22)) break;
          __builtin_amdgcn_s_sleep(1);
        }
      }
      f32x4 acc[4];
#pragma unroll
      for (int i = 0; i < 4; ++i) acc[i] = (f32x4){0.f, 0.f, 0.f, 0.f};
#pragma unroll
      for (int kt = 0; kt < 3; ++kt) {
        f32x4 x0 = *(const f32x4*)&xbuf[s & 1][lc][kt * 32 + kg * 8];
        f32x4 x1 = *(const f32x4*)&xbuf[s & 1][lc][kt * 32 + kg * 8 + 4];
        short8 axh, axl;
#pragma unroll
        for (int jj = 0; jj < 4; ++jj) {
          unsigned short hb = f2bf(x0[jj]);
          axh[jj] = (short)hb;
          axl[jj] = (short)f2bf(x0[jj] - bf2f(hb));
          unsigned short hb2 = f2bf(x1[jj]);
          axh[jj + 4] = (short)hb2;
          axl[jj + 4] = (short)f2bf(x1[jj] - bf2f(hb2));
        }
        acc[(3 * kt) & 3] = __builtin_amdgcn_mfma_f32_16x16x32_bf16(axh, xwh[kt], acc[(3 * kt) & 3], 0, 0, 0);
        acc[(3 * kt + 1) & 3] = __builtin_amdgcn_mfma_f32_16x16x32_bf16(axl, xwh[kt], acc[(3 * kt + 1) & 3], 0, 0, 0);
        acc[(3 * kt + 2) & 3] = __builtin_amdgcn_mfma_f32_16x16x32_bf16(axh, xwl[kt], acc[(3 * kt + 2) & 3], 0, 0, 0);
      }
      lgkm0();
      if (l == 0) { if (w == 0) xcons0 = s + 1; else xcons1 = s + 1; }

      if (s) {
        // ---- spin: all 64 publisher flags of my group (agent loads, proven) ----
        if (!noSync) {
          int guard = 0;
          for (;;) {
            unsigned int v = __hip_atomic_load(watch, __ATOMIC_RELAXED, __HIP_MEMORY_SCOPE_AGENT);
            if (!__any((int)v < s)) break;
            if ((++guard & 255) == 0) {
              if (__hip_atomic_load(abortw, __ATOMIC_RELAXED, __HIP_MEMORY_SCOPE_AGENT) != 0u ||
                  guard > (1 << 16)) {
                __hip_atomic_store(abortw, 1u, __ATOMIC_RELAXED, __HIP_MEMORY_SCOPE_AGENT);
                noSync = true;
                break;
              }
            }
            __builtin_amdgcn_s_sleep(1);
          }
        }
        asm volatile("" ::: "memory");

        // ---- full-K A-stream: 4 chunks x 8 k-tiles, double-buffered, counted waits ----
        const char* srcg = (const char*)hy_ex + (size_t)(rb * 8 + g) * 65536;
        u64x2 Ah0[8], Al0[8], Ah1[8], Al1[8];
        ISSUE(0, Ah0, Al0);
        ISSUE(1, Ah1, Al1);
        vmw16();
        CRUNCH(0, Ah0, Al0);
        ISSUE(2, Ah0, Al0);
        vmw16();
        CRUNCH(1, Ah1, Al1);
        ISSUE(3, Ah1, Al1);
        vmw16();
        CRUNCH(2, Ah0, Al0);
        vmw0();
        CRUNCH(3, Ah1, Al1);
      }

      // ---- state update + publish (16 cols, pair-packed) ----
      f32x4 r = (acc[0] + acc[1]) + (acc[2] + acc[3]);
      unsigned int* dstg = hy_ex + (size_t)(wb * 8 + g) * 16384;
#pragma unroll
      for (int i = 0; i < 4; ++i) {
        float a = r[i] + bias_c;
        float th = fast_tanhf(a);
        hz[i] += DT * (th - gam * hy[i] - ep * hz[i]);
        hy[i] += DT * hz[i];
        const int rr = kg * 4 + i;
        unsigned short hb = f2bf(hy[i]);
        unsigned short lb = f2bf(hy[i] - bf2f(hb));
        unsigned int oh = (unsigned int)__shfl_xor((int)hb, 1, 64);
        unsigned int ol = (unsigned int)__shfl_xor((int)lb, 1, 64);
        if (!(lc & 1)) {
          const int u32i = rr * 512 + (myc >> 1);
          st4<F>(dstg + u32i, (unsigned int)hb | (oh << 16));
          st4<F>(dstg + 8192 + u32i, (unsigned int)lb | (ol << 16));
        }
      }
      vmw0();  // queue = my 8 publish stores only (L2/IC ack, fast)
      if (l == 0)
        __hip_atomic_store(myflag, (unsigned int)(s + 1), __ATOMIC_RELAXED,
                           __HIP_MEMORY_SCOPE_AGENT);

      // ---- hy handoff to out-service wave (LDS; off critical path) ----
      if (s >= 2) {
        int gu = 0;
        while (outsq < s - 1) {
          if (++gu > (1 << 22)) break;
          __builtin_amdgcn_s_sleep(1);
        }
      }
#pragma unroll
      for (int i = 0; i < 4; ++i) hybuf[s & 1][w][kg * 4 + i][lc] = hy[i];
      lgkm0();
      if (l == 0) { if (w == 0) hyseq0 = s + 1; else hyseq1 = s + 1; }
    }
  };

  if (fastm)
    run(BoolC<true>{});
  else
    run(BoolC<false>{});
#undef ISSUE
#undef CRUNCH
}

extern "C" void kernel_launch(void* const* d_in, const int* in_sizes, int n_in,
                              void* d_out, int out_size, void* d_ws, size_t ws_size,
                              hipStream_t stream) {
  const float* x = (const float*)d_in[0];
  const float* x2h = (const float*)d_in[1];
  const float* h2h = (const float*)d_in[2];
  const float* bias = (const float*)d_in[3];
  const float* gam = (const float*)d_in[4];
  const float* eps = (const float*)d_in[5];
  float* out = (float*)d_out;

  unsigned int* flags = (unsigned int*)d_ws;                   // 32KB flags + tables
  unsigned int* hy_ex = (unsigned int*)((char*)d_ws + 65536);  // 3 x 8 x 64KB = 1.5MB

  hipMemsetAsync(d_ws, 0, 65536, stream);

  ron_kernel<<<dim3(256), dim3(256), 0, stream>>>(x, x2h, h2h, bias, gam, eps, out, flags, hy_ex);
}

// Round 15
// 2717.569 us; speedup vs baseline: 4.5552x; 1.2298x over previous
//
#include <hip/hip_runtime.h>
#include <math.h>

typedef short short8 __attribute__((ext_vector_type(8)));
typedef float f32x4 __attribute__((ext_vector_type(4)));
typedef unsigned long long u64;
typedef u64 u64x2 __attribute__((ext_vector_type(2)));

#define DT 0.042f
#define LSEQ 512
#define NI 96
#define NH 1024

static __device__ __forceinline__ unsigned short f2bf(float f) {
  unsigned int u = __builtin_bit_cast(unsigned int, f);
  return (unsigned short)((u + 0x7fffu + ((u >> 16) & 1u)) >> 16);
}
static __device__ __forceinline__ float bf2f(unsigned short h) {
  unsigned int u = ((unsigned int)h) << 16;
  return __builtin_bit_cast(float, u);
}
static __device__ __forceinline__ float fast_tanhf(float a) {
  float ax = __builtin_fabsf(a);
  float e = __expf(2.0f * ax);
  float t = 1.0f - 2.0f / (e + 1.0f);
  return a < 0.0f ? -t : t;
}

// DATA: sc0 (XCD L2) on verified co-XCD groups [r8]; agent/IC otherwise [r5].
// FLAGS: relaxed agent atomics only (r9 sc0=L1-sticky, r11 RMW=collapse, r13 inv=slow).
template <bool F>
static __device__ __forceinline__ void ld16_issue(u64x2* dst, const u64* p) {
  if constexpr (F) {
    asm volatile("global_load_dwordx4 %0, %1, off sc0" : "=v"(*dst) : "v"(p) : "memory");
  } else {
    u64 a = __hip_atomic_load(p, __ATOMIC_RELAXED, __HIP_MEMORY_SCOPE_AGENT);
    u64 b = __hip_atomic_load(p + 1, __ATOMIC_RELAXED, __HIP_MEMORY_SCOPE_AGENT);
    *dst = (u64x2){a, b};
  }
}
template <bool F>
static __device__ __forceinline__ void stpub(unsigned int* p, unsigned int v) {
  if constexpr (F)
    asm volatile("global_store_dword %0, %1, off sc0" ::"v"(p), "v"(v) : "memory");
  else
    __hip_atomic_store(p, v, __ATOMIC_RELAXED, __HIP_MEMORY_SCOPE_AGENT);
}
static __device__ __forceinline__ void drain_vm() {
  asm volatile("s_waitcnt vmcnt(0)" ::: "memory");
  __builtin_amdgcn_sched_barrier(0);
}
static __device__ __forceinline__ void lgkm0() {
  asm volatile("s_waitcnt lgkmcnt(0)" ::: "memory");
  __builtin_amdgcn_sched_barrier(0);
}
template <bool B> struct BoolC { static constexpr bool value = B; };

// 256 blocks x 576 threads (9 waves). Group g (16 rows) x col-block jb (32 cols).
// Waves 0-7: r10's proven compute (k-split, per-wave flags, single barrier/step,
// triple-buffered hy_ex) — but their VMEM queues now hold ONLY fast-ack ops
// (IC polls, L2 A-loads, L2 publishes, flag store). Wave 8 = service: owns ALL
// HBM traffic (x HBM->LDS [stride 100 = conflict-free], hy LDS->out DRAM).
// LDS seq-words (lgkm domain) decouple service from compute vmcnt queues —
// removes the r8/r10 hidden stall where each poll's vmcnt(0) waited DRAM acks.
__global__ __launch_bounds__(576, 1) void ron_kernel(
    const float* __restrict__ x, const float* __restrict__ x2h,
    const float* __restrict__ h2h, const float* __restrict__ bias,
    const float* __restrict__ gam_, const float* __restrict__ eps_,
    float* __restrict__ out, unsigned int* __restrict__ flags,
    unsigned int* __restrict__ hy_ex) {
  const int tid = threadIdx.x;
  const int w = tid >> 6;  // 0..8
  const int l = tid & 63;
  const int lc = l & 15;
  const int kg = l >> 4;

  __shared__ f32x4 part[2][8][2][64];   // 32KB
  __shared__ float xbuf[2][16][100];    // 12.5KB, stride 100 f32 -> 2-way (free)
  __shared__ float hybuf[2][2][16][16]; // 4KB
  __shared__ int info_sh;
  __shared__ volatile int xseq, xcons0, xcons1, hyseq0, hyseq1, outsq;

  unsigned int* base = flags + 8192;  // byte 32768
  unsigned int* xcdtab = base;
  unsigned int* ctr = base + 256;
  unsigned int* abortw = base + 257;
  unsigned int* enttab = base + 272;

  if (tid == 0) {
    xseq = 0; xcons0 = 0; xcons1 = 0; hyseq0 = 0; hyseq1 = 0; outsq = 0;
    unsigned int myxcd = __builtin_amdgcn_s_getreg(63508) & 15u;  // XCC_ID
    __hip_atomic_store(xcdtab + blockIdx.x, 0x100u | myxcd, __ATOMIC_RELAXED,
                       __HIP_MEMORY_SCOPE_AGENT);
    __hip_atomic_fetch_add(ctr, 1u, __ATOMIC_RELAXED, __HIP_MEMORY_SCOPE_AGENT);
  }

  // ---- block 0: build (g, jb, mode) table — single source of truth (r8-proven) ----
  if (blockIdx.x == 0 && tid == 0) {
    int gu = 0;
    while (__hip_atomic_load(ctr, __ATOMIC_RELAXED, __HIP_MEMORY_SCOPE_AGENT) < 256u) {
      if (++gu > (1 << 17)) break;
      __builtin_amdgcn_s_sleep(8);
    }
    bool ok = (gu <= (1 << 17));
    unsigned char xs[256];
    if (ok) {
      for (int i = 0; i < 256; ++i) {
        unsigned int v = __hip_atomic_load(xcdtab + i, __ATOMIC_RELAXED, __HIP_MEMORY_SCOPE_AGENT);
        int g2 = 0;
        while (v == 0 && ++g2 <= 8192) {
          __builtin_amdgcn_s_sleep(2);
          v = __hip_atomic_load(xcdtab + i, __ATOMIC_RELAXED, __HIP_MEMORY_SCOPE_AGENT);
        }
        if (v == 0) { ok = false; break; }
        xs[i] = (unsigned char)(v & 15u);
      }
    }
    unsigned int ent[256];
    if (ok) {
      int gidx = 0, nl = 0;
      unsigned char left[256], tmp[256];
      for (unsigned int xc = 0; xc < 16u && gidx < 8; ++xc) {
        int cnt = 0;
        for (int i = 0; i < 256; ++i)
          if (xs[i] == (unsigned char)xc) tmp[cnt++] = (unsigned char)i;
        int p = 0;
        while (cnt - p >= 32 && gidx < 8) {
          for (int k2 = 0; k2 < 32; ++k2)
            ent[tmp[p + k2]] = 1u | ((unsigned)gidx << 1) | ((unsigned)k2 << 4) | (1u << 9);
          ++gidx; p += 32;
        }
        for (; p < cnt; ++p) left[nl++] = tmp[p];
      }
      int li = 0;
      while (gidx < 8) {
        for (int k2 = 0; k2 < 32 && li < nl; ++k2, ++li)
          ent[left[li]] = 1u | ((unsigned)gidx << 1) | ((unsigned)k2 << 4);
        ++gidx;
      }
    } else {
      for (int i = 0; i < 256; ++i)
        ent[i] = 1u | ((unsigned)(i & 7) << 1) | ((unsigned)(i >> 3) << 4);
    }
    for (int i = 0; i < 256; ++i)
      __hip_atomic_store(enttab + i, ent[i], __ATOMIC_RELAXED, __HIP_MEMORY_SCOPE_AGENT);
  }

  if (tid == 0) {
    unsigned int e = 0;
    int gu = 0;
    for (;;) {
      e = __hip_atomic_load(enttab + blockIdx.x, __ATOMIC_RELAXED, __HIP_MEMORY_SCOPE_AGENT);
      if (e || ++gu > (1 << 17)) break;
      __builtin_amdgcn_s_sleep(16);
    }
    if (!e) e = 1u | ((unsigned)(blockIdx.x & 7) << 1) | ((unsigned)(blockIdx.x >> 3) << 4);
    info_sh = (int)e;
  }
  __syncthreads();
  const unsigned int ent = (unsigned int)info_sh;
  const int g = (ent >> 1) & 7;
  const int jb = (ent >> 4) & 31;
  const bool fastm = ((ent >> 9) & 1) != 0;

#define LSPIN(COND)                                   \
  if (!noLds) {                                       \
    int gu_ = 0;                                      \
    while (COND) {                                    \
      if (++gu_ > (1 << 17)) { noLds = true; break; } \
      __builtin_amdgcn_s_sleep(1);                    \
    }                                                 \
    asm volatile("" ::: "memory");                    \
  }

  // ================= SERVICE WAVE (w == 8): all HBM traffic =================
  if (w == 8) {
    bool noLds = false;
    for (int t = 0; t < LSEQ; ++t) {
      if (t >= 2) { LSPIN(xcons0 < t - 1 || xcons1 < t - 1) }
      f32x4 v[6];
#pragma unroll
      for (int k = 0; k < 6; ++k) {
        const int u = l + 64 * k;  // 384 dwordx4 units: row u/24, offset (u%24)*4 f32
        const float* p = x + ((size_t)(g * 16 + u / 24) * LSEQ + t) * NI + (u % 24) * 4;
        v[k] = *(const f32x4*)p;
      }
      if (t >= 1) {  // out[t-1] from hybuf
        LSPIN(hyseq0 < t || hyseq1 < t)
        const int row = l >> 2, q = l & 3, wv = q >> 1, c0 = (q & 1) * 8;
        f32x4 a = *(const f32x4*)&hybuf[(t - 1) & 1][wv][row][c0];
        f32x4 b = *(const f32x4*)&hybuf[(t - 1) & 1][wv][row][c0 + 4];
        lgkm0();
        if (l == 0) outsq = t;  // hybuf[(t-1)&1] free for rewrite
        float* po = out + ((size_t)(g * 16 + row) * LSEQ + (t - 1)) * NH + jb * 32 + q * 8;
        *(f32x4*)po = a;
        *(f32x4*)(po + 4) = b;
      }
#pragma unroll
      for (int k = 0; k < 6; ++k) {
        const int u = l + 64 * k;
        *(f32x4*)&xbuf[t & 1][u / 24][(u % 24) * 4] = v[k];
      }
      lgkm0();
      if (l == 0) xseq = t + 1;
      __syncthreads();  // one barrier per iteration (matches compute waves)
    }
    // flush final step's output
    {
      bool dummy = noLds; noLds = dummy;
      LSPIN(hyseq0 < LSEQ || hyseq1 < LSEQ)
      const int row = l >> 2, q = l & 3, wv = q >> 1, c0 = (q & 1) * 8;
      f32x4 a = *(const f32x4*)&hybuf[(LSEQ - 1) & 1][wv][row][c0];
      f32x4 b = *(const f32x4*)&hybuf[(LSEQ - 1) & 1][wv][row][c0 + 4];
      float* po = out + ((size_t)(g * 16 + row) * LSEQ + (LSEQ - 1)) * NH + jb * 32 + q * 8;
      *(f32x4*)po = a;
      *(f32x4*)(po + 4) = b;
    }
    return;
  }

  // ================= COMPUTE WAVES (w = 0..7) =================
  short8 wfh[4][2], wfl[4][2];
#pragma unroll
  for (int j = 0; j < 4; ++j) {
    const int krow = (w * 4 + j) * 32 + kg * 8;
#pragma unroll
    for (int t = 0; t < 2; ++t) {
      const int c = jb * 32 + t * 16 + lc;
#pragma unroll
      for (int jj = 0; jj < 8; ++jj) {
        float v = h2h[(size_t)(krow + jj) * NH + c];
        unsigned short hb = f2bf(v);
        wfh[j][t][jj] = (short)hb;
        wfl[j][t][jj] = (short)f2bf(v - bf2f(hb));
      }
    }
  }
  const int myc = jb * 32 + w * 16 + lc;  // owned col (waves 0,1 only)
  short8 xwh[3], xwl[3];
  float bias_c = 0.f, gam = 0.f, ep = 0.f;
  if (w < 2) {
#pragma unroll
    for (int kt = 0; kt < 3; ++kt)
#pragma unroll
      for (int jj = 0; jj < 8; ++jj) {
        float v = x2h[(size_t)(kt * 32 + kg * 8 + jj) * NH + myc];
        unsigned short hb = f2bf(v);
        xwh[kt][jj] = (short)hb;
        xwl[kt][jj] = (short)f2bf(v - bf2f(hb));
      }
    bias_c = bias[myc];
    gam = gam_[myc];
    ep = eps_[myc];
  }

  float hy[4] = {0.f, 0.f, 0.f, 0.f};
  float hz[4] = {0.f, 0.f, 0.f, 0.f};
  const int aoff = lc * 8 + kg * 2;  // u64 units within a 128-u64 chunk
  unsigned int* myflag = flags + (size_t)(g * 64 + jb * 2 + w) * 16;
  unsigned int* watch =
      flags + (size_t)(g * 64 + (w * 4 + ((l >> 1) & 3)) * 2 + (l & 1)) * 16;
  const int ktc = myc >> 5, kgc = (myc >> 3) & 3, sh = myc & 7;

  auto run = [&](auto fc) {
    constexpr bool F = decltype(fc)::value;
    bool noSync = false, noLds = false;
    for (int s = 0; s < LSEQ; ++s) {
      const int wb = s % 3, rb = wb ? wb - 1 : 2;

      u64x2 hq[4], lq[4];
      if (s) {
        // ---- spin: my 4 suppliers x 2 pub-waves (agent loads; queue is clean) ----
        if (!noSync) {
          int guard = 0;
          for (;;) {
            unsigned int v = __hip_atomic_load(watch, __ATOMIC_RELAXED, __HIP_MEMORY_SCOPE_AGENT);
            if (!__any((int)v < s)) break;
            if ((++guard & 255) == 0) {
              if (__hip_atomic_load(abortw, __ATOMIC_RELAXED, __HIP_MEMORY_SCOPE_AGENT) != 0u ||
                  guard > (1 << 16)) {
                __hip_atomic_store(abortw, 1u, __ATOMIC_RELAXED, __HIP_MEMORY_SCOPE_AGENT);
                noSync = true;
                break;
              }
            }
            __builtin_amdgcn_s_sleep(1);
          }
        }
        asm volatile("" ::: "memory");
        // ---- issue A-loads (L2-fast) ----
        const u64* srcg = (const u64*)hy_ex + (size_t)(rb * 8 + g) * 8192;
#pragma unroll
        for (int j = 0; j < 4; ++j) {
          const int idx = (w * 4 + j) * 128 + aoff;
          ld16_issue<F>(&hq[j], srcg + idx);
          ld16_issue<F>(&lq[j], srcg + 4096 + idx);
        }
      }

      // ---- x from LDS (waves 0,1): pack + 9 MFMAs overlap the A-load RT ----
      f32x4 accx = {0.f, 0.f, 0.f, 0.f};
      if (w < 2) {
        LSPIN(xseq < s + 1)
#pragma unroll
        for (int kt = 0; kt < 3; ++kt) {
          f32x4 x0 = *(const f32x4*)&xbuf[s & 1][lc][kt * 32 + kg * 8];
          f32x4 x1 = *(const f32x4*)&xbuf[s & 1][lc][kt * 32 + kg * 8 + 4];
          short8 axh, axl;
#pragma unroll
          for (int jj = 0; jj < 4; ++jj) {
            unsigned short hb = f2bf(x0[jj]);
            axh[jj] = (short)hb;
            axl[jj] = (short)f2bf(x0[jj] - bf2f(hb));
            unsigned short hb2 = f2bf(x1[jj]);
            axh[jj + 4] = (short)hb2;
            axl[jj + 4] = (short)f2bf(x1[jj] - bf2f(hb2));
          }
          accx = __builtin_amdgcn_mfma_f32_16x16x32_bf16(axh, xwh[kt], accx, 0, 0, 0);
          accx = __builtin_amdgcn_mfma_f32_16x16x32_bf16(axl, xwh[kt], accx, 0, 0, 0);
          accx = __builtin_amdgcn_mfma_f32_16x16x32_bf16(axh, xwl[kt], accx, 0, 0, 0);
        }
        lgkm0();
        if (l == 0) { if (w == 0) xcons0 = s + 1; else xcons1 = s + 1; }
      }

      f32x4 a0a = {0.f, 0.f, 0.f, 0.f}, a0b = {0.f, 0.f, 0.f, 0.f};
      f32x4 a1a = {0.f, 0.f, 0.f, 0.f}, a1b = {0.f, 0.f, 0.f, 0.f};
      if (s) {
        drain_vm();  // A ready — queue holds ONLY A-loads (L2) + flag store
#pragma unroll
        for (int j = 0; j < 4; ++j) {
          short8 fh = __builtin_bit_cast(short8, hq[j]);
          short8 fl = __builtin_bit_cast(short8, lq[j]);
          if (j & 1) {
            a0b = __builtin_amdgcn_mfma_f32_16x16x32_bf16(fh, wfh[j][0], a0b, 0, 0, 0);
            a1b = __builtin_amdgcn_mfma_f32_16x16x32_bf16(fh, wfh[j][1], a1b, 0, 0, 0);
            a0b = __builtin_amdgcn_mfma_f32_16x16x32_bf16(fl, wfh[j][0], a0b, 0, 0, 0);
            a1b = __builtin_amdgcn_mfma_f32_16x16x32_bf16(fl, wfh[j][1], a1b, 0, 0, 0);
            a0b = __builtin_amdgcn_mfma_f32_16x16x32_bf16(fh, wfl[j][0], a0b, 0, 0, 0);
            a1b = __builtin_amdgcn_mfma_f32_16x16x32_bf16(fh, wfl[j][1], a1b, 0, 0, 0);
          } else {
            a0a = __builtin_amdgcn_mfma_f32_16x16x32_bf16(fh, wfh[j][0], a0a, 0, 0, 0);
            a1a = __builtin_amdgcn_mfma_f32_16x16x32_bf16(fh, wfh[j][1], a1a, 0, 0, 0);
            a0a = __builtin_amdgcn_mfma_f32_16x16x32_bf16(fl, wfh[j][0], a0a, 0, 0, 0);
            a1a = __builtin_amdgcn_mfma_f32_16x16x32_bf16(fl, wfh[j][1], a1a, 0, 0, 0);
            a0a = __builtin_amdgcn_mfma_f32_16x16x32_bf16(fh, wfl[j][0], a0a, 0, 0, 0);
            a1a = __builtin_amdgcn_mfma_f32_16x16x32_bf16(fh, wfl[j][1], a1a, 0, 0, 0);
          }
        }
      }

      part[s & 1][w][0][l] = a0a + a0b;
      part[s & 1][w][1][l] = a1a + a1b;
      __syncthreads();  // the single per-step barrier

      if (w < 2) {
        f32x4 r = accx;
#pragma unroll
        for (int ww = 0; ww < 8; ++ww) r += part[s & 1][ww][w][l];

        unsigned int* dstg = hy_ex + (size_t)(wb * 8 + g) * 16384;
#pragma unroll
        for (int i = 0; i < 4; ++i) {
          float a = r[i] + bias_c;
          float th = fast_tanhf(a);
          hz[i] += DT * (th - gam * hy[i] - ep * hz[i]);
          hy[i] += DT * hz[i];
          const int rr = kg * 4 + i;
          unsigned short hb = f2bf(hy[i]);
          unsigned short lb = f2bf(hy[i] - bf2f(hb));
          unsigned int oh = (unsigned int)__shfl_xor((int)hb, 1, 64);
          unsigned int ol = (unsigned int)__shfl_xor((int)lb, 1, 64);
          if (!(lc & 1)) {
            const int u32idx = (ktc * 512 + rr * 32 + kgc * 8 + sh) >> 1;
            stpub<F>(dstg + u32idx, (unsigned int)hb | (oh << 16));
            stpub<F>(dstg + 8192 + u32idx, (unsigned int)lb | (ol << 16));
          }
        }
        drain_vm();  // publishes L2/IC-acked — fast (no DRAM in this queue)
        if (l == 0)
          __hip_atomic_store(myflag, (unsigned int)(s + 1), __ATOMIC_RELAXED,
                             __HIP_MEMORY_SCOPE_AGENT);

        // ---- hy handoff to service wave (LDS, off the inter-block path) ----
        if (s >= 2) { LSPIN(outsq < s - 1) }
#pragma unroll
        for (int i = 0; i < 4; ++i) hybuf[s & 1][w][kg * 4 + i][lc] = hy[i];
        lgkm0();
        if (l == 0) { if (w == 0) hyseq0 = s + 1; else hyseq1 = s + 1; }
      }
    }
  };

  if (fastm)
    run(BoolC<true>{});
  else
    run(BoolC<false>{});
#undef LSPIN
}

extern "C" void kernel_launch(void* const* d_in, const int* in_sizes, int n_in,
                              void* d_out, int out_size, void* d_ws, size_t ws_size,
                              hipStream_t stream) {
  const float* x = (const float*)d_in[0];
  const float* x2h = (const float*)d_in[1];
  const float* h2h = (const float*)d_in[2];
  const float* bias = (const float*)d_in[3];
  const float* gam = (const float*)d_in[4];
  const float* eps = (const float*)d_in[5];
  float* out = (float*)d_out;

  unsigned int* flags = (unsigned int*)d_ws;                   // 32KB flags + tables
  unsigned int* hy_ex = (unsigned int*)((char*)d_ws + 65536);  // 3 x 8 x 64KB = 1.5MB

  hipMemsetAsync(d_ws, 0, 65536, stream);

  ron_kernel<<<dim3(256), dim3(576), 0, stream>>>(x, x2h, h2h, bias, gam, eps, out, flags, hy_ex);
}

// Round 16
// 1798.852 us; speedup vs baseline: 6.8816x; 1.5107x over previous
//
#include <hip/hip_runtime.h>
#include <math.h>

typedef short short8 __attribute__((ext_vector_type(8)));
typedef float f32x4 __attribute__((ext_vector_type(4)));
typedef unsigned long long u64;
typedef u64 u64x2 __attribute__((ext_vector_type(2)));

#define DT 0.042f
#define LSEQ 512
#define NI 96
#define NH 1024

static __device__ __forceinline__ unsigned short f2bf(float f) {
  unsigned int u = __builtin_bit_cast(unsigned int, f);
  return (unsigned short)((u + 0x7fffu + ((u >> 16) & 1u)) >> 16);
}
static __device__ __forceinline__ float bf2f(unsigned short h) {
  unsigned int u = ((unsigned int)h) << 16;
  return __builtin_bit_cast(float, u);
}
static __device__ __forceinline__ float fast_tanhf(float a) {
  float ax = __builtin_fabsf(a);
  float e = __expf(2.0f * ax);  // overflow -> inf -> t = 1, no NaN
  float t = 1.0f - 2.0f / (e + 1.0f);
  return a < 0.0f ? -t : t;
}

// ---- DATA ops only are scope-templated. Flags ALWAYS use proven agent atomics (IC).
// F=true: sc0 (XCD-local L2) for hy_ex data — valid only for verified co-XCD groups.
template <bool F>
static __device__ __forceinline__ void ld16_issue(u64x2* dst, const u64* p) {
  if constexpr (F) {
    asm volatile("global_load_dwordx4 %0, %1, off sc0" : "=v"(*dst) : "v"(p) : "memory");
  } else {
    u64 a = __hip_atomic_load(p, __ATOMIC_RELAXED, __HIP_MEMORY_SCOPE_AGENT);
    u64 b = __hip_atomic_load(p + 1, __ATOMIC_RELAXED, __HIP_MEMORY_SCOPE_AGENT);
    *dst = (u64x2){a, b};
  }
}
template <bool F>
static __device__ __forceinline__ void ld_fence() {  // A-frags resident (rule #18)
  if constexpr (F) {
    asm volatile("s_waitcnt vmcnt(0)" ::: "memory");
    __builtin_amdgcn_sched_barrier(0);
  }
}
template <bool F>
static __device__ __forceinline__ void stpub(unsigned int* p, unsigned int v) {
  if constexpr (F)
    asm volatile("global_store_dword %0, %1, off sc0" ::"v"(p), "v"(v) : "memory");
  else
    __hip_atomic_store(p, v, __ATOMIC_RELAXED, __HIP_MEMORY_SCOPE_AGENT);
}
static __device__ __forceinline__ void drain_vm() {  // explicit: publishes committed
  asm volatile("s_waitcnt vmcnt(0)" ::: "memory");
  __builtin_amdgcn_sched_barrier(0);
}
template <bool B> struct BoolC { static constexpr bool value = B; };

// 256 blocks x 512 threads. Group g (16 batch rows) x col-block jb (32 cols); 8 waves
// k-split 1024; per-wave watch of its 4 suppliers + triple buffering (r5 invariant:
// union of the 8 waves' watch sets = all 32 producers -> buffer (s-3)%3 fully read).
// Mapping (g, jb, fast) from a table built by block 0 from ACTUAL XCD placement;
// exact-32 co-XCD sets -> fast (hy_ex data via sc0 in that XCD's L2), else slow
// (agent/IC data path, byte-proven in round 5). Flags always agent/IC (proven).
// Explicit vmcnt(0) drain before the barrier that precedes each flag post.
__global__ __launch_bounds__(512, 2) void ron_kernel(
    const float* __restrict__ x, const float* __restrict__ x2h,
    const float* __restrict__ h2h, const float* __restrict__ bias,
    const float* __restrict__ gam_, const float* __restrict__ eps_,
    float* __restrict__ out, unsigned int* __restrict__ flags,
    unsigned int* __restrict__ hy_ex) {
  const int tid = threadIdx.x;
  const int w = tid >> 6;  // 0..7
  const int l = tid & 63;
  const int lc = l & 15;
  const int kg = l >> 4;

  __shared__ f32x4 part[8][2][64];  // 16KB
  __shared__ int info_sh;

  unsigned int* base = flags + 4096;  // byte 16384
  unsigned int* xcdtab = base;        // [0..255]
  unsigned int* ctr = base + 256;
  unsigned int* abortw = base + 257;
  unsigned int* enttab = base + 272;  // [0..255]

  // ---- publish my XCD (every block) ----
  if (tid == 0) {
    unsigned int myxcd = __builtin_amdgcn_s_getreg(63508) & 15u;  // hwreg(XCC_ID=20,0,32)
    __hip_atomic_store(xcdtab + blockIdx.x, 0x100u | myxcd, __ATOMIC_RELAXED,
                       __HIP_MEMORY_SCOPE_AGENT);
    __hip_atomic_fetch_add(ctr, 1u, __ATOMIC_RELAXED, __HIP_MEMORY_SCOPE_AGENT);
  }

  // ---- block 0: build the (g, jb, mode) table — single source of truth ----
  if (blockIdx.x == 0 && tid == 0) {
    int gu = 0;
    while (__hip_atomic_load(ctr, __ATOMIC_RELAXED, __HIP_MEMORY_SCOPE_AGENT) < 256u) {
      if (++gu > (1 << 17)) break;  // ~75ms
      __builtin_amdgcn_s_sleep(8);
    }
    bool ok = (gu <= (1 << 17));
    unsigned char xs[256];
    if (ok) {
      for (int i = 0; i < 256; ++i) {
        unsigned int v = __hip_atomic_load(xcdtab + i, __ATOMIC_RELAXED, __HIP_MEMORY_SCOPE_AGENT);
        int g2 = 0;
        while (v == 0 && ++g2 <= 8192) {
          __builtin_amdgcn_s_sleep(2);
          v = __hip_atomic_load(xcdtab + i, __ATOMIC_RELAXED, __HIP_MEMORY_SCOPE_AGENT);
        }
        if (v == 0) { ok = false; break; }
        xs[i] = (unsigned char)(v & 15u);
      }
    }
    unsigned int ent[256];
    if (ok) {
      int gidx = 0, nl = 0;
      unsigned char left[256], tmp[256];
      for (unsigned int xc = 0; xc < 16u && gidx < 8; ++xc) {
        int cnt = 0;
        for (int i = 0; i < 256; ++i)
          if (xs[i] == (unsigned char)xc) tmp[cnt++] = (unsigned char)i;
        int p = 0;
        while (cnt - p >= 32 && gidx < 8) {  // exact-32 co-XCD set -> fast
          for (int k2 = 0; k2 < 32; ++k2)
            ent[tmp[p + k2]] = 1u | ((unsigned)gidx << 1) | ((unsigned)k2 << 4) | (1u << 9);
          ++gidx; p += 32;
        }
        for (; p < cnt; ++p) left[nl++] = tmp[p];
      }
      int li = 0;
      while (gidx < 8) {  // mixed leftovers -> slow (proven protocol)
        for (int k2 = 0; k2 < 32 && li < nl; ++k2, ++li)
          ent[left[li]] = 1u | ((unsigned)gidx << 1) | ((unsigned)k2 << 4);
        ++gidx;
      }
    } else {
      for (int i = 0; i < 256; ++i)
        ent[i] = 1u | ((unsigned)(i & 7) << 1) | ((unsigned)(i >> 3) << 4);
    }
    for (int i = 0; i < 256; ++i)
      __hip_atomic_store(enttab + i, ent[i], __ATOMIC_RELAXED, __HIP_MEMORY_SCOPE_AGENT);
  }

  // ---- every block: fetch my entry (long guard -> partial timeout ~impossible) ----
  if (tid == 0) {
    unsigned int e = 0;
    int gu = 0;
    for (;;) {
      e = __hip_atomic_load(enttab + blockIdx.x, __ATOMIC_RELAXED, __HIP_MEMORY_SCOPE_AGENT);
      if (e || ++gu > (1 << 17)) break;  // ~150ms
      __builtin_amdgcn_s_sleep(16);
    }
    if (!e) e = 1u | ((unsigned)(blockIdx.x & 7) << 1) | ((unsigned)(blockIdx.x >> 3) << 4);
    info_sh = (int)e;
  }
  __syncthreads();
  const unsigned int ent = (unsigned int)info_sh;
  const int g = (ent >> 1) & 7;
  const int jb = (ent >> 4) & 31;
  const bool fastm = ((ent >> 9) & 1) != 0;

  // ---- one-time: h2h k-slice (wave's 4 k-tiles) x 2 col-tiles, hi/lo bf16 ----
  short8 wfh[4][2], wfl[4][2];
#pragma unroll
  for (int j = 0; j < 4; ++j) {
    const int krow = (w * 4 + j) * 32 + kg * 8;
#pragma unroll
    for (int t = 0; t < 2; ++t) {
      const int c = jb * 32 + t * 16 + lc;
#pragma unroll
      for (int jj = 0; jj < 8; ++jj) {
        float v = h2h[(size_t)(krow + jj) * NH + c];
        unsigned short hb = f2bf(v);
        wfh[j][t][jj] = (short)hb;
        wfl[j][t][jj] = (short)f2bf(v - bf2f(hb));
      }
    }
  }
  const int myc = jb * 32 + w * 16 + lc;  // owned col (waves 0,1 only)
  short8 xwh[3], xwl[3];
  float bias_c = 0.f, gam = 0.f, ep = 0.f;
  if (w < 2) {
#pragma unroll
    for (int kt = 0; kt < 3; ++kt)
#pragma unroll
      for (int jj = 0; jj < 8; ++jj) {
        float v = x2h[(size_t)(kt * 32 + kg * 8 + jj) * NH + myc];
        unsigned short hb = f2bf(v);
        xwh[kt][jj] = (short)hb;
        xwl[kt][jj] = (short)f2bf(v - bf2f(hb));
      }
    bias_c = bias[myc];
    gam = gam_[myc];
    ep = eps_[myc];
  }

  float hy[4] = {0.f, 0.f, 0.f, 0.f};
  float hz[4] = {0.f, 0.f, 0.f, 0.f};
  const float* xlane = x + (size_t)(g * 16 + lc) * LSEQ * NI + kg * 8;
  const int aoff = lc * 8 + kg * 2;  // u64 units within a 128-u64 chunk
  unsigned int* myflag = flags + (size_t)(g * 32 + jb) * 16;              // 64B-spaced
  unsigned int* watch = flags + (size_t)(g * 32 + w * 4 + (l & 3)) * 16;  // wave's 4 suppliers
  const int ktc = myc >> 5, kgc = (myc >> 3) & 3, sh = myc & 7;

  // ---- prefetch x for s=0 ----
  f32x4 xr[6];
  if (w < 2) {
#pragma unroll
    for (int kt = 0; kt < 3; ++kt) {
      xr[2 * kt] = *(const f32x4*)(xlane + kt * 32);
      xr[2 * kt + 1] = *(const f32x4*)(xlane + kt * 32 + 4);
    }
  }

  auto run = [&](auto fc) {
    constexpr bool F = decltype(fc)::value;
    bool noSync = false;  // watchdog: trip -> never wait again (fast, visible failure)
    for (int s = 0; s < LSEQ; ++s) {
      const int wb = s % 3;            // write buffer
      const int rb = wb ? wb - 1 : 2;  // read buffer = (s-1)%3

      // ---- pack x(s) frags from prefetched regs (x(s+1) prefetch happens at iter end) ----
      short8 axh[3], axl[3];
      if (w < 2) {
#pragma unroll
        for (int kt = 0; kt < 3; ++kt) {
#pragma unroll
          for (int jj = 0; jj < 4; ++jj) {
            unsigned short hb = f2bf(xr[2 * kt][jj]);
            axh[kt][jj] = (short)hb;
            axl[kt][jj] = (short)f2bf(xr[2 * kt][jj] - bf2f(hb));
            unsigned short hb2 = f2bf(xr[2 * kt + 1][jj]);
            axh[kt][jj + 4] = (short)hb2;
            axl[kt][jj + 4] = (short)f2bf(xr[2 * kt + 1][jj] - bf2f(hb2));
          }
        }
      }

      f32x4 a0a = {0.f, 0.f, 0.f, 0.f}, a0b = {0.f, 0.f, 0.f, 0.f};
      f32x4 a1a = {0.f, 0.f, 0.f, 0.f}, a1b = {0.f, 0.f, 0.f, 0.f};
      f32x4 accx = {0.f, 0.f, 0.f, 0.f};
      u64x2 hq[4], lq[4];

      if (s) {
        // ---- wait for this wave's 4 suppliers (agent/IC flags — proven) ----
        if (!noSync) {
          int guard = 0;
          for (;;) {
            unsigned int v = __hip_atomic_load(watch, __ATOMIC_RELAXED, __HIP_MEMORY_SCOPE_AGENT);
            if (!__any((int)v < s)) break;
            if ((++guard & 255) == 0) {
              if (__hip_atomic_load(abortw, __ATOMIC_RELAXED, __HIP_MEMORY_SCOPE_AGENT) != 0u ||
                  guard > (1 << 16)) {
                __hip_atomic_store(abortw, 1u, __ATOMIC_RELAXED, __HIP_MEMORY_SCOPE_AGENT);
                noSync = true;
                break;
              }
            }
            __builtin_amdgcn_s_sleep(1);
          }
        }
        asm volatile("" ::: "memory");  // keep A-loads below the spin

        // ---- issue A-fragment loads (wave's k-quarter: 8 x 16B) ----
        const u64* srcg = (const u64*)hy_ex + (size_t)(rb * 8 + g) * 8192;
#pragma unroll
        for (int j = 0; j < 4; ++j) {
          const int idx = (w * 4 + j) * 128 + aoff;
          ld16_issue<F>(&hq[j], srcg + idx);
          ld16_issue<F>(&lq[j], srcg + 4096 + idx);
        }
      }

      // ---- x-projection MFMAs (waves 0,1): overlap the A-load round trip ----
      if (w < 2) {
#pragma unroll
        for (int kt = 0; kt < 3; ++kt) {
          accx = __builtin_amdgcn_mfma_f32_16x16x32_bf16(axh[kt], xwh[kt], accx, 0, 0, 0);
          accx = __builtin_amdgcn_mfma_f32_16x16x32_bf16(axl[kt], xwh[kt], accx, 0, 0, 0);
          accx = __builtin_amdgcn_mfma_f32_16x16x32_bf16(axh[kt], xwl[kt], accx, 0, 0, 0);
        }
      }

      if (s) {
        ld_fence<F>();  // fast: vmcnt(0) — x(s+1) was issued last iter, already complete
#pragma unroll
        for (int j = 0; j < 4; ++j) {
          short8 fh = __builtin_bit_cast(short8, hq[j]);
          short8 fl = __builtin_bit_cast(short8, lq[j]);
          if (j & 1) {
            a0b = __builtin_amdgcn_mfma_f32_16x16x32_bf16(fh, wfh[j][0], a0b, 0, 0, 0);
            a1b = __builtin_amdgcn_mfma_f32_16x16x32_bf16(fh, wfh[j][1], a1b, 0, 0, 0);
            a0b = __builtin_amdgcn_mfma_f32_16x16x32_bf16(fl, wfh[j][0], a0b, 0, 0, 0);
            a1b = __builtin_amdgcn_mfma_f32_16x16x32_bf16(fl, wfh[j][1], a1b, 0, 0, 0);
            a0b = __builtin_amdgcn_mfma_f32_16x16x32_bf16(fh, wfl[j][0], a0b, 0, 0, 0);
            a1b = __builtin_amdgcn_mfma_f32_16x16x32_bf16(fh, wfl[j][1], a1b, 0, 0, 0);
          } else {
            a0a = __builtin_amdgcn_mfma_f32_16x16x32_bf16(fh, wfh[j][0], a0a, 0, 0, 0);
            a1a = __builtin_amdgcn_mfma_f32_16x16x32_bf16(fh, wfh[j][1], a1a, 0, 0, 0);
            a0a = __builtin_amdgcn_mfma_f32_16x16x32_bf16(fl, wfh[j][0], a0a, 0, 0, 0);
            a1a = __builtin_amdgcn_mfma_f32_16x16x32_bf16(fl, wfh[j][1], a1a, 0, 0, 0);
            a0a = __builtin_amdgcn_mfma_f32_16x16x32_bf16(fh, wfl[j][0], a0a, 0, 0, 0);
            a1a = __builtin_amdgcn_mfma_f32_16x16x32_bf16(fh, wfl[j][1], a1a, 0, 0, 0);
          }
        }
      }

      // ---- cross-wave k-reduction via LDS ----
      part[w][0][l] = a0a + a0b;
      part[w][1][l] = a1a + a1b;
      __syncthreads();

      if (w < 2) {
        f32x4 r = accx;
#pragma unroll
        for (int ww = 0; ww < 8; ++ww) r += part[ww][w][l];

        unsigned int* dstg = hy_ex + (size_t)(wb * 8 + g) * 16384;
#pragma unroll
        for (int i = 0; i < 4; ++i) {
          float a = r[i] + bias_c;
          float th = fast_tanhf(a);
          hz[i] += DT * (th - gam * hy[i] - ep * hz[i]);
          hy[i] += DT * hz[i];
          const int rr = kg * 4 + i;
          unsigned short hb = f2bf(hy[i]);
          unsigned short lb = f2bf(hy[i] - bf2f(hb));
          unsigned int oh = (unsigned int)__shfl_xor((int)hb, 1, 64);
          unsigned int ol = (unsigned int)__shfl_xor((int)lb, 1, 64);
          if (!(lc & 1)) {  // even col stores the (c, c+1) pair
            const int u32idx = (ktc * 512 + rr * 32 + kgc * 8 + sh) >> 1;
            stpub<F>(dstg + u32idx, (unsigned int)hb | (oh << 16));
            stpub<F>(dstg + 8192 + u32idx, (unsigned int)lb | (ol << 16));
          }
        }
      }

      drain_vm();       // EXPLICIT: publish stores committed before anyone posts the flag
      __syncthreads();  // all 8 waves drained
      if (tid == 0)
        __hip_atomic_store(myflag, (unsigned int)(s + 1), __ATOMIC_RELAXED,
                           __HIP_MEMORY_SCOPE_AGENT);

      // ---- off the critical path: out[] stores, then x(s+1) prefetch ----
      if (w < 2) {
#pragma unroll
        for (int i = 0; i < 4; ++i)
          out[((size_t)(g * 16 + kg * 4 + i) * LSEQ + s) * NH + myc] = hy[i];
        const float* xs2 = xlane + (size_t)(s + 1 < LSEQ ? s + 1 : s) * NI;
#pragma unroll
        for (int kt = 0; kt < 3; ++kt) {
          xr[2 * kt] = *(const f32x4*)(xs2 + kt * 32);
          xr[2 * kt + 1] = *(const f32x4*)(xs2 + kt * 32 + 4);
        }
      }
    }
  };

  if (fastm)
    run(BoolC<true>{});
  else
    run(BoolC<false>{});
}

extern "C" void kernel_launch(void* const* d_in, const int* in_sizes, int n_in,
                              void* d_out, int out_size, void* d_ws, size_t ws_size,
                              hipStream_t stream) {
  const float* x = (const float*)d_in[0];
  const float* x2h = (const float*)d_in[1];
  const float* h2h = (const float*)d_in[2];
  const float* bias = (const float*)d_in[3];
  const float* gam = (const float*)d_in[4];
  const float* eps = (const float*)d_in[5];
  float* out = (float*)d_out;

  unsigned int* flags = (unsigned int*)d_ws;                   // 16KB flags + discovery/table
  unsigned int* hy_ex = (unsigned int*)((char*)d_ws + 32768);  // 3 bufs x 8 groups x 64KB

  // zero flags + discovery + mapping table every call (step 0 never reads hy_ex)
  hipMemsetAsync(d_ws, 0, 32768, stream);

  ron_kernel<<<dim3(256), dim3(512), 0, stream>>>(x, x2h, h2h, bias, gam, eps, out, flags, hy_ex);
}